// Round 6
// baseline (677.557 us; speedup 1.0000x reference)
//
#include <hip/hip_runtime.h>
#include <hip/hip_bf16.h>
#include <type_traits>

// B=4, S=4096, H=1024, NH=8, HD=128, L=64 ; d = NH*HD = 1024
// M = B*S = 16384, K = N = 1024 for all five GEMMs.
#define GATE_ELEMS 16777216ull   // 16384 * 1024
#define W_ELEMS    1048576ull    // 1024 * 1024

typedef float f32x4 __attribute__((ext_vector_type(4)));
typedef short s16x8 __attribute__((ext_vector_type(8)));
typedef unsigned short u16;

__device__ __forceinline__ u16 f2bf(float f) {
  union { float f; unsigned u; } v; v.f = f;
  unsigned r = v.u + 0x7fffu + ((v.u >> 16) & 1u);   // RNE round to bf16
  return (u16)(r >> 16);
}
__device__ __forceinline__ float bf2f(u16 u) {
  union { unsigned u; float f; } v; v.u = ((unsigned)u) << 16;
  return v.f;
}
__device__ __forceinline__ float sigmoidf_(float x) {
  return 1.0f / (1.0f + __expf(-x));
}
__device__ __forceinline__ float tanhf_(float x) {
  x = fminf(fmaxf(x, -15.f), 15.f);
  const float e = __expf(2.f * x);
  return (e - 1.f) / (e + 1.f);
}

__device__ __forceinline__ void load_lds16(const u16* g, u16* l) {
  __builtin_amdgcn_global_load_lds(
      (const __attribute__((address_space(1))) unsigned int*)g,
      (__attribute__((address_space(3))) unsigned int*)l, 16, 0, 0);
}

// ---------------------------------------------------------------------------
// Merged fp32 -> bf16 converter for the 4 X inputs and 5 weight matrices.
// Grid-stride, 16-B chunks (8 floats -> 8 bf16).
// ---------------------------------------------------------------------------
#define XCHUNKS 8388608u   // 4 * GATE_ELEMS / 8
#define WCHUNKS 655360u    // 5 * W_ELEMS / 8
__global__ void cvt_all(const float* __restrict__ x0, const float* __restrict__ x1,
                        const float* __restrict__ x2, const float* __restrict__ x3,
                        const float* __restrict__ w0, const float* __restrict__ w1,
                        const float* __restrict__ w2, const float* __restrict__ w3,
                        const float* __restrict__ w4,
                        u16* __restrict__ xdst, u16* __restrict__ wdst) {
  const unsigned total = XCHUNKS + WCHUNKS;
  for (unsigned i = blockIdx.x * 256 + threadIdx.x; i < total; i += 2048 * 256) {
    const float* s; u16* d; size_t loc;
    if (i < XCHUNKS) {
      const int w = i >> 21;                       // GATE_ELEMS/8 = 1<<21
      loc = (size_t)(i & 2097151u) * 8;
      s = (w == 0) ? x0 : (w == 1) ? x1 : (w == 2) ? x2 : x3;
      d = xdst + (size_t)w * GATE_ELEMS;
    } else {
      const unsigned j = i - XCHUNKS;
      const int w = j >> 17;                       // W_ELEMS/8 = 1<<17
      loc = (size_t)(j & 131071u) * 8;
      s = (w == 0) ? w0 : (w == 1) ? w1 : (w == 2) ? w2 : (w == 3) ? w3 : w4;
      d = wdst + (size_t)w * W_ELEMS;
    }
    const float4 a = *reinterpret_cast<const float4*>(s + loc);
    const float4 b = *reinterpret_cast<const float4*>(s + loc + 4);
    s16x8 wv;
    wv[0] = (short)f2bf(a.x); wv[1] = (short)f2bf(a.y);
    wv[2] = (short)f2bf(a.z); wv[3] = (short)f2bf(a.w);
    wv[4] = (short)f2bf(b.x); wv[5] = (short)f2bf(b.y);
    wv[6] = (short)f2bf(b.z); wv[7] = (short)f2bf(b.w);
    *reinterpret_cast<s16x8*>(d + loc) = wv;
  }
}

// ---------------------------------------------------------------------------
// bf16 GEMM, T3 "minimum 2-phase" structure:
//   BM=BN=128, BK=64, 4 waves (2x2), per-wave 64x64 (4x4 frags, 2 kk),
//   double-buffered 64 KB LDS, ONE barrier per K-iter (16 iters),
//   G4 XOR swizzle (16-B slot ^= row&7) via inverse-swizzled global source
//   (global_load_lds writes linearly) + swizzled ds_read.
// C[m,n] = sum_k A[m,k]*B[n,k] + bias[n];  M=16384, N=1024, K=1024 fixed.
// LDS u16 layout: [buf(2)][mat(2)][row(128)][slot(8)^ (row&7)][8]
// ---------------------------------------------------------------------------
__device__ __forceinline__ void stage_mat(const u16* __restrict__ M, int R0, int kt,
                                          u16* ldsbase, int tid) {
#pragma unroll
  for (int l = 0; l < 4; ++l) {
    const int T  = l * 256 + tid;          // 0..1023 16-B slots of the tile
    const int r  = T >> 3;                 // 0..127
    const int sl = (T & 7) ^ (r & 7);      // logical 16-B slot (inverse swizzle)
    load_lds16(M + (size_t)(R0 + r) * 1024 + kt + sl * 8,
               ldsbase + (T & ~63) * 8);   // wave-uniform base; HW adds lane*16B
  }
}

template <typename OT>
__global__ __launch_bounds__(256, 2)
void gemm_bt128(const u16* __restrict__ A, const u16* __restrict__ Bm,
                const float* __restrict__ bias, OT* __restrict__ C) {
  extern __shared__ u16 lds[];             // 2 * 2 * 8192 u16 = 64 KiB
  const int tid  = threadIdx.x;
  const int lane = tid & 63;
  const int wave = tid >> 6;
  const int wr = wave >> 1;
  const int wc = wave & 1;
  const int frow = lane & 15;
  const int kq   = lane >> 4;

  // bijective XCD swizzle; grid = 1024 (128 m-tiles x 8 n-tiles), m-major
  int bid = blockIdx.x;
  bid = (bid & 7) * 128 + (bid >> 3);
  const int m0 = (bid >> 3) * 128;
  const int n0 = (bid & 7) * 128;

  f32x4 acc[4][4];
#pragma unroll
  for (int i = 0; i < 4; ++i)
#pragma unroll
    for (int j = 0; j < 4; ++j)
      acc[i][j] = (f32x4){0.f, 0.f, 0.f, 0.f};

  stage_mat(A,  m0, 0, lds,        tid);
  stage_mat(Bm, n0, 0, lds + 8192, tid);
  __syncthreads();

  int cur = 0;
#pragma unroll 2
  for (int t = 0; t < 16; ++t) {
    if (t < 15) {
      u16* nb = lds + (cur ^ 1) * 16384;
      stage_mat(A,  m0, (t + 1) * 64, nb,        tid);
      stage_mat(Bm, n0, (t + 1) * 64, nb + 8192, tid);
    }
    const u16* Ab = lds + cur * 16384;
    const u16* Bb = Ab + 8192;
#pragma unroll
    for (int kk = 0; kk < 2; ++kk) {
      s16x8 a[4], b[4];
#pragma unroll
      for (int mf = 0; mf < 4; ++mf) {
        const int r  = wr * 64 + mf * 16 + frow;
        const int ps = (kk * 4 + kq) ^ (r & 7);
        a[mf] = *reinterpret_cast<const s16x8*>(&Ab[r * 64 + ps * 8]);
      }
#pragma unroll
      for (int nf = 0; nf < 4; ++nf) {
        const int r  = wc * 64 + nf * 16 + frow;
        const int ps = (kk * 4 + kq) ^ (r & 7);
        b[nf] = *reinterpret_cast<const s16x8*>(&Bb[r * 64 + ps * 8]);
      }
#pragma unroll
      for (int mf = 0; mf < 4; ++mf)
#pragma unroll
        for (int nf = 0; nf < 4; ++nf)
          acc[mf][nf] = __builtin_amdgcn_mfma_f32_16x16x32_bf16(a[mf], b[nf], acc[mf][nf], 0, 0, 0);
    }
    __syncthreads();          // compiler emits vmcnt(0) lgkmcnt(0) drain here
    cur ^= 1;
  }

  // epilogue: C/D layout col = lane&15, row = (lane>>4)*4 + r
#pragma unroll
  for (int nf = 0; nf < 4; ++nf) {
    const int col = n0 + wc * 64 + nf * 16 + frow;
    const float bv = bias[col];
#pragma unroll
    for (int mf = 0; mf < 4; ++mf) {
      const int rbase = m0 + wr * 64 + mf * 16 + kq * 4;
#pragma unroll
      for (int r = 0; r < 4; ++r) {
        const float v = acc[mf][nf][r] + bv;
        if constexpr (std::is_same<OT, float>::value)
          C[(size_t)(rbase + r) * 1024 + col] = v;
        else
          C[(size_t)(rbase + r) * 1024 + col] = f2bf(v);
      }
    }
  }
}

// ---------------------------------------------------------------------------
// Scan pass 1: 4 channels/thread. P = prod f, cl = local response (c0=0).
// ---------------------------------------------------------------------------
__global__ void scan_pass1(const u16* __restrict__ fx, const u16* __restrict__ ix,
                           const u16* __restrict__ zx,
                           float* __restrict__ P, float* __restrict__ cl) {
  const int t  = blockIdx.x * 256 + threadIdx.x;   // 0..65535
  const int jg = (t & 255) * 4;
  const int q  = (t >> 8) & 63;
  const int b  = t >> 14;
  const size_t base = ((size_t)(b * 4096 + q * 64)) * 1024 + jg;
  float Pp[4] = {1.f, 1.f, 1.f, 1.f};
  float c[4]  = {0.f, 0.f, 0.f, 0.f};
  for (int s = 0; s < 64; ++s) {
    const size_t o = base + (size_t)s * 1024;
    const ushort4 fv = *reinterpret_cast<const ushort4*>(fx + o);
    const ushort4 iv = *reinterpret_cast<const ushort4*>(ix + o);
    const ushort4 zv = *reinterpret_cast<const ushort4*>(zx + o);
    const u16* fp = (const u16*)&fv;
    const u16* ip = (const u16*)&iv;
    const u16* zp = (const u16*)&zv;
#pragma unroll
    for (int k = 0; k < 4; ++k) {
      const float f = sigmoidf_(bf2f(fp[k]) + 1.f);
      const float u = sigmoidf_(bf2f(ip[k])) * tanhf_(bf2f(zp[k]));
      Pp[k] *= f;
      c[k] = f * c[k] + u;
    }
  }
  const int sidx = q * 4096 + b * 1024 + jg;
  *reinterpret_cast<float4*>(P + sidx)  = make_float4(Pp[0], Pp[1], Pp[2], Pp[3]);
  *reinterpret_cast<float4*>(cl + sidx) = make_float4(c[0], c[1], c[2], c[3]);
}

// ---------------------------------------------------------------------------
// Scan pass 2: per-channel scan over 64 chunk summaries; carries + last_c.
// ---------------------------------------------------------------------------
__global__ void scan_pass2(const float* __restrict__ P, const float* __restrict__ cl,
                           const float* __restrict__ c0, float* __restrict__ cin,
                           float* __restrict__ lastc) {
  const int idx = blockIdx.x * 256 + threadIdx.x;  // 0..4095
  float carry = c0[idx];
#pragma unroll
  for (int q = 0; q < 64; ++q) {
    const int s = q * 4096 + idx;
    cin[s] = carry;
    carry = fmaf(P[s], carry, cl[s]);
  }
  lastc[idx] = carry;
}

// ---------------------------------------------------------------------------
// Scan pass 3: replay with correct carry, compute h (bf16) + last_h.
// ---------------------------------------------------------------------------
__global__ void scan_pass3(const u16* __restrict__ fx, const u16* __restrict__ ix,
                           const u16* __restrict__ zx, const u16* __restrict__ ox,
                           const float* __restrict__ cin,
                           u16* __restrict__ h, float* __restrict__ lasth) {
  const int t  = blockIdx.x * 256 + threadIdx.x;
  const int jg = (t & 255) * 4;
  const int q  = (t >> 8) & 63;
  const int b  = t >> 14;
  const size_t base = ((size_t)(b * 4096 + q * 64)) * 1024 + jg;
  const float4 ci = *reinterpret_cast<const float4*>(cin + q * 4096 + b * 1024 + jg);
  float c[4]  = {ci.x, ci.y, ci.z, ci.w};
  float hv[4] = {0.f, 0.f, 0.f, 0.f};
  for (int s = 0; s < 64; ++s) {
    const size_t o = base + (size_t)s * 1024;
    const ushort4 fv = *reinterpret_cast<const ushort4*>(fx + o);
    const ushort4 iv = *reinterpret_cast<const ushort4*>(ix + o);
    const ushort4 zv = *reinterpret_cast<const ushort4*>(zx + o);
    const ushort4 ov = *reinterpret_cast<const ushort4*>(ox + o);
    const u16* fp = (const u16*)&fv;
    const u16* ip = (const u16*)&iv;
    const u16* zp = (const u16*)&zv;
    const u16* op = (const u16*)&ov;
    ushort4 hw;
    u16* hp = (u16*)&hw;
#pragma unroll
    for (int k = 0; k < 4; ++k) {
      const float f = sigmoidf_(bf2f(fp[k]) + 1.f);
      const float u = sigmoidf_(bf2f(ip[k])) * tanhf_(bf2f(zp[k]));
      c[k] = f * c[k] + u;
      hv[k] = sigmoidf_(bf2f(op[k])) * tanhf_(c[k]);
      hp[k] = f2bf(hv[k]);
    }
    *reinterpret_cast<ushort4*>(h + o) = hw;
  }
  if (q == 63)
    *reinterpret_cast<float4*>(lasth + b * 1024 + jg) =
        make_float4(hv[0], hv[1], hv[2], hv[3]);
}

// ---------------------------------------------------------------------------
extern "C" void kernel_launch(void* const* d_in, const int* in_sizes, int n_in,
                              void* d_out, int out_size, void* d_ws, size_t ws_size,
                              hipStream_t stream) {
  const float* xin[4]  = {(const float*)d_in[0], (const float*)d_in[1],
                          (const float*)d_in[2], (const float*)d_in[3]};
  const float* c0      = (const float*)d_in[4];
  const float* W[5]    = {(const float*)d_in[6], (const float*)d_in[8],
                          (const float*)d_in[10], (const float*)d_in[12],
                          (const float*)d_in[14]};
  const float* bias[5] = {(const float*)d_in[7], (const float*)d_in[9],
                          (const float*)d_in[11], (const float*)d_in[13],
                          (const float*)d_in[15]};
  float* out = (float*)d_out;

  (void)hipFuncSetAttribute((const void*)gemm_bt128<u16>,
                            hipFuncAttributeMaxDynamicSharedMemorySize, 65536);
  (void)hipFuncSetAttribute((const void*)gemm_bt128<float>,
                            hipFuncAttributeMaxDynamicSharedMemorySize, 65536);

  // Workspace (~149 MB): xbf[4] (reused as gate buffers / h), wbf[5], summaries.
  u16* xbf = (u16*)d_ws;
  u16* wbf = xbf + 4 * GATE_ELEMS;
  float* Pbuf   = (float*)(wbf + 5 * W_ELEMS);
  float* clbuf  = Pbuf + 262144;
  float* cinbuf = clbuf + 262144;

  u16* gp[4];
  gp[0] = (u16*)d_out;            // gate0 in d_out scratch (consumed pre-final-GEMM)
  gp[1] = xbf;                    // xbf[0] dead after GEMM 0
  gp[2] = xbf + GATE_ELEMS;       // xbf[1] dead after GEMM 1
  gp[3] = xbf + 2 * GATE_ELEMS;   // xbf[2] dead after GEMM 2
  u16* h = xbf + 3 * GATE_ELEMS;  // xbf[3] dead after GEMM 3

  cvt_all<<<2048, 256, 0, stream>>>(xin[0], xin[1], xin[2], xin[3],
                                    W[0], W[1], W[2], W[3], W[4], xbf, wbf);

  for (int g = 0; g < 4; ++g)
    gemm_bt128<u16><<<1024, 256, 65536, stream>>>(
        xbf + (size_t)g * GATE_ELEMS, wbf + (size_t)g * W_ELEMS, bias[g], gp[g]);

  scan_pass1<<<256, 256, 0, stream>>>(gp[0], gp[1], gp[2], Pbuf, clbuf);
  scan_pass2<<<16, 256, 0, stream>>>(Pbuf, clbuf, c0, cinbuf, out + GATE_ELEMS);
  scan_pass3<<<256, 256, 0, stream>>>(gp[0], gp[1], gp[2], gp[3], cinbuf, h,
                                      out + GATE_ELEMS + 4096);

  gemm_bt128<float><<<1024, 256, 65536, stream>>>(h, wbf + 4 * W_ELEMS, bias[4], out);
}